// Round 7
// baseline (266.637 us; speedup 1.0000x reference)
//
#include <hip/hip_runtime.h>
#include <stdint.h>
#include <limits.h>

// ---------------------------------------------------------------------------
// RPN loss, bit-exact replication of the JAX reference (incl. threefry PRNG).
// Round 6b: same as round 6 (occupancy + inner-loop trims on the verified r5
// structure), with the compile fix: fp-contract pragma moved into an
// area_of() helper (pragma must open a compound statement).
//  - label_k: block=64 -> 4608 single-wave blocks = exactly 18 waves/CU.
//    Count reduce = wave shuffle, once, outside the g-loop. area_g
//    precomputed into LDS (bit-identical product), area_a hoisted.
//  - best_anchor_k: 4-way anchor split (grid 1024x4, 16 blocks/CU), 4 ILP
//    chains; one fire-and-forget packed-u64 atomicMax per block.
// Rule from r3/r4: no cross-thread communication inside the g-loop.
// pack = iou_bits<<32 | ~a : max == (higher iou, then smaller anchor index).
// ---------------------------------------------------------------------------
#define PARTITIONABLE 1

#define B_ 8
#define K_ 9
#define H_ 64
#define W_ 64
#define G_ 128
#define A_ 36864            // K*H*W
#define HALF_A 18432
#define QUART_A 9216
#define NBUCK 8192          // buckets over 23-bit v (v>>10)
#define CAP 1024            // cutoff-bucket candidate capacity (expected ~5)

struct KeyParams { uint32_t k[B_][4]; };   // per image: k1.(0,1), k2.(0,1)

__host__ __device__ static inline uint32_t rotl32(uint32_t x, int r) {
  return (x << r) | (x >> (32 - r));
}

// JAX threefry2x32: 20 rounds, key injections every 4 rounds.
__host__ __device__ static inline void tf2x32(uint32_t k0, uint32_t k1,
                                              uint32_t x0, uint32_t x1,
                                              uint32_t& o0, uint32_t& o1) {
  uint32_t ks2 = k0 ^ k1 ^ 0x1BD11BDAu;
  x0 += k0; x1 += k1;
#define TF_R(r) { x0 += x1; x1 = rotl32(x1, r); x1 ^= x0; }
  TF_R(13) TF_R(15) TF_R(26) TF_R(6)
  x0 += k1;  x1 += ks2 + 1u;
  TF_R(17) TF_R(29) TF_R(16) TF_R(24)
  x0 += ks2; x1 += k0 + 2u;
  TF_R(13) TF_R(15) TF_R(26) TF_R(6)
  x0 += k0;  x1 += k1 + 3u;
  TF_R(17) TF_R(29) TF_R(16) TF_R(24)
  x0 += k1;  x1 += ks2 + 4u;
  TF_R(13) TF_R(15) TF_R(26) TF_R(6)
  x0 += ks2; x1 += k0 + 5u;
#undef TF_R
  o0 = x0; o1 = x1;
}

// 23-bit sort key of jax.random.uniform(key,(A,))[a]; score monotone in v,
// score ties <=> equal v (stable argsort -> smaller index ranks first).
__device__ static inline uint32_t anchor_vbits(uint32_t k0, uint32_t k1, int a) {
  uint32_t o0, o1;
#if PARTITIONABLE
  tf2x32(k0, k1, 0u, (uint32_t)a, o0, o1);
  return (o0 ^ o1) >> 9;
#else
  if (a < HALF_A) { tf2x32(k0, k1, (uint32_t)a, (uint32_t)(a + HALF_A), o0, o1); return o0 >> 9; }
  else            { tf2x32(k0, k1, (uint32_t)(a - HALF_A), (uint32_t)a, o0, o1); return o1 >> 9; }
#endif
}

// Box area, contraction off (bit-identical to XLA's plain fp32 ops).
__device__ static inline float area_of(float x0, float y0, float x1, float y1) {
#pragma clang fp contract(off)
  return (x1 - x0) * (y1 - y0);
}

// IoU, contraction off to match XLA-CPU plain IEEE fp32 op-by-op.
__device__ static inline float iou_fn(float a0, float a1, float a2, float a3,
                                      float g0, float g1, float g2, float g3) {
#pragma clang fp contract(off)
  float ltx = fmaxf(a0, g0), lty = fmaxf(a1, g1);
  float rbx = fminf(a2, g2), rby = fminf(a3, g3);
  float w = rbx - ltx; w = (w < 0.f) ? 0.f : w;
  float h = rby - lty; h = (h < 0.f) ? 0.f : h;
  float inter  = w * h;
  float area_a = (a2 - a0) * (a3 - a1);
  float area_g = (g2 - g0) * (g3 - g1);
  return inter / (area_a + area_g - inter + 1e-6f);
}

// Variant with both areas precomputed (bit-identical products, XLA order).
__device__ static inline float iou_pre(float a0, float a1, float a2, float a3,
                                       float area_a,
                                       float g0, float g1, float g2, float g3,
                                       float area_g) {
#pragma clang fp contract(off)
  float ltx = fmaxf(a0, g0), lty = fmaxf(a1, g1);
  float rbx = fminf(a2, g2), rby = fminf(a3, g3);
  float w = rbx - ltx; w = (w < 0.f) ? 0.f : w;
  float h = rby - lty; h = (h < 0.f) ? 0.f : h;
  float inter = w * h;
  return inter / (area_a + area_g - inter + 1e-6f);
}

__device__ static inline void encode4(float4 an, float4 gg, float* tt) {
#pragma clang fp contract(off)
  float aw  = an.z - an.x,            ah  = an.w - an.y;
  float acx = (an.x + an.z) * 0.5f,   acy = (an.y + an.w) * 0.5f;
  float gw  = gg.z - gg.x,            gh  = gg.w - gg.y;
  float gcx = (gg.x + gg.z) * 0.5f,   gcy = (gg.y + gg.w) * 0.5f;
  tt[0] = (gcx - acx) / aw;
  tt[1] = (gcy - acy) / ah;
  tt[2] = logf(gw / aw);
  tt[3] = logf(gh / ah);
}

__device__ static inline float block_reduce_float(float v, float* sh) {
  int t = threadIdx.x;
  sh[t] = v; __syncthreads();
  for (int s = 128; s > 0; s >>= 1) { if (t < s) sh[t] += sh[t + s]; __syncthreads(); }
  float r = sh[0]; __syncthreads();
  return r;
}

__device__ static inline unsigned long long pack_vi(float v, int a) {
  return ((unsigned long long)__float_as_uint(v) << 32) | (uint32_t)(~(uint32_t)a);
}

// K1: per (b,g) x anchor-quarter: first-occurrence argmax over anchors of IoU.
// 4 independent accumulator chains for ILP; block-reduce packed u64; one
// fire-and-forget global atomicMax per block (4096 total -> no contention).
__global__ __launch_bounds__(256) void best_anchor_k(const float* __restrict__ anchors,
                                                     const float* __restrict__ gtb,
                                                     unsigned long long* __restrict__ gmax) {
  const int bg = blockIdx.x;              // b*G + g
  const int base = blockIdx.y * QUART_A;  // anchor quarter
  float4 gg = ((const float4*)gtb)[bg];
  float v0 = -1.f, v1 = -1.f, v2 = -1.f, v3 = -1.f;
  int   i0 = 0,    i1 = 0,    i2 = 0,    i3 = 0;
  // QUART_A/1024 = 9 full iterations; each stream is increasing-a, so
  // strict > keeps the first (smallest) index within the stream.
  for (int a = base + threadIdx.x; a < base + QUART_A; a += 1024) {
    float4 an0 = ((const float4*)anchors)[a];
    float4 an1 = ((const float4*)anchors)[a + 256];
    float4 an2 = ((const float4*)anchors)[a + 512];
    float4 an3 = ((const float4*)anchors)[a + 768];
    float w0 = iou_fn(an0.x, an0.y, an0.z, an0.w, gg.x, gg.y, gg.z, gg.w);
    float w1 = iou_fn(an1.x, an1.y, an1.z, an1.w, gg.x, gg.y, gg.z, gg.w);
    float w2 = iou_fn(an2.x, an2.y, an2.z, an2.w, gg.x, gg.y, gg.z, gg.w);
    float w3 = iou_fn(an3.x, an3.y, an3.z, an3.w, gg.x, gg.y, gg.z, gg.w);
    if (w0 > v0) { v0 = w0; i0 = a; }
    if (w1 > v1) { v1 = w1; i1 = a + 256; }
    if (w2 > v2) { v2 = w2; i2 = a + 512; }
    if (w3 > v3) { v3 = w3; i3 = a + 768; }
  }
  // combine: packed max == (higher iou, then smaller anchor index)
  unsigned long long p = pack_vi(v0, i0);
  unsigned long long q = pack_vi(v1, i1); if (q > p) p = q;
  q = pack_vi(v2, i2); if (q > p) p = q;
  q = pack_vi(v3, i3); if (q > p) p = q;
  __shared__ unsigned long long sp[256];
  sp[threadIdx.x] = p; __syncthreads();
  for (int s = 128; s > 0; s >>= 1) {
    if (threadIdx.x < s) { if (sp[threadIdx.x + s] > sp[threadIdx.x]) sp[threadIdx.x] = sp[threadIdx.x + s]; }
    __syncthreads();
  }
  if (threadIdx.x == 0) atomicMax(&gmax[bg], sp[0]);   // no-return, once/block
}

// K2: per (b,a): label, matched gt (first-wins), PRNG keys; fused global
// histogram (pre-force) + wave-reduced pos/neg counts. Block=64 (one wave):
// 4608 blocks = exactly 18 waves/CU, perfectly balanced. NO cross-thread
// work inside the g-loop (r3/r4 lesson).
__global__ __launch_bounds__(64) void label_k(const float* __restrict__ anchors,
                                              const float* __restrict__ gtb,
                                              int* __restrict__ labels,
                                              int* __restrict__ mgt,
                                              uint32_t* __restrict__ vpos,
                                              uint32_t* __restrict__ vneg,
                                              int* __restrict__ ghist,
                                              int* __restrict__ counts,
                                              KeyParams kp) {
  __shared__ float4 gts[G_];
  __shared__ float  gar[G_];
  const int b = blockIdx.y;
  const int t = threadIdx.x;
  for (int i = t; i < G_; i += 64) {
    float4 gg = ((const float4*)gtb)[b * G_ + i];
    gts[i] = gg;
    gar[i] = area_of(gg.x, gg.y, gg.z, gg.w);
  }
  __syncthreads();
  const int a = blockIdx.x * 64 + t;      // < A_ exactly (A_/64 = 576)
  float4 an = ((const float4*)anchors)[a];
  float area_a = area_of(an.x, an.y, an.z, an.w);
  float bv = -1.f; int bi = 0;
#pragma unroll 4
  for (int g = 0; g < G_; g++) {
    float4 gg = gts[g];
    float v = iou_pre(an.x, an.y, an.z, an.w, area_a,
                      gg.x, gg.y, gg.z, gg.w, gar[g]);
    if (v > bv) { bv = v; bi = g; }       // first-occurrence argmax over g
  }
  int lb = (bv < 0.3f) ? 0 : ((bv >= 0.7f) ? 1 : -1);
  size_t idx = (size_t)b * A_ + a;
  uint32_t vp = anchor_vbits(kp.k[b][0], kp.k[b][1], a);
  uint32_t vn = anchor_vbits(kp.k[b][2], kp.k[b][3], a);
  labels[idx] = lb;
  mgt[idx]    = bi;
  vpos[idx]   = vp;
  vneg[idx]   = vn;
  if (lb == 1)      atomicAdd(&ghist[(b * 2 + 0) * NBUCK + (vp >> 10)], 1);
  else if (lb == 0) atomicAdd(&ghist[(b * 2 + 1) * NBUCK + (vn >> 10)], 1);
  // packed counts: pos | neg<<16 (wave sums <= 64, safe); single wave ->
  // butterfly shuffle, no barrier.
  int packed = (lb == 1 ? 1 : 0) | ((lb == 0 ? 1 : 0) << 16);
  packed += __shfl_xor(packed, 1);
  packed += __shfl_xor(packed, 2);
  packed += __shfl_xor(packed, 4);
  packed += __shfl_xor(packed, 8);
  packed += __shfl_xor(packed, 16);
  packed += __shfl_xor(packed, 32);
  if (t == 0) {
    atomicAdd(&counts[b * 2 + 0], packed & 0xFFFF);
    atomicAdd(&counts[b * 2 + 1], packed >> 16);
  }
}

// K3: force best anchor per gt to 1; patch counts + histograms incrementally.
// atomicExch detects the first forcing of a shared anchor.
__global__ void force_k(const unsigned long long* __restrict__ gmax,
                        int* __restrict__ labels,
                        const uint32_t* __restrict__ vpos,
                        const uint32_t* __restrict__ vneg,
                        int* __restrict__ ghist,
                        int* __restrict__ counts) {
  int tg = blockIdx.x * 256 + threadIdx.x;   // < B_*G_ exactly (4 blocks)
  int b = tg / G_;
  int a = (int)(~(uint32_t)(gmax[tg] & 0xFFFFFFFFull));
  size_t idx = (size_t)b * A_ + a;
  int old = atomicExch(&labels[idx], 1);
  if (old != 1) {
    atomicAdd(&counts[b * 2 + 0], 1);
    atomicAdd(&ghist[(b * 2 + 0) * NBUCK + (vpos[idx] >> 10)], 1);
    if (old == 0) {
      atomicSub(&counts[b * 2 + 1], 1);
      atomicSub(&ghist[(b * 2 + 1) * NBUCK + (vneg[idx] >> 10)], 1);
    }
  }
}

// K4: per (b,c): target + exact cutoff bucket cb and in-bucket remainder R.
__global__ __launch_bounds__(256) void cutoff_k(const int* __restrict__ ghist,
                                                const int* __restrict__ counts,
                                                int* __restrict__ cbR,
                                                int* __restrict__ targets) {
  const int row = blockIdx.x;               // b*2 + c
  const int b = row >> 1, c = row & 1;
  const int t = threadIdx.x;
  __shared__ int seg[256];
  int npos = counts[b * 2 + 0], nneg = counts[b * 2 + 1];
  int tp = npos < 128 ? npos : 128;
  int tn = 256 - tp; if (nneg < tn) tn = nneg;
  const int target = (c == 0) ? tp : tn;
  const int* hist = ghist + (size_t)row * NBUCK;
  { int s = 0; const int base = t * 32;
    for (int i = 0; i < 32; i++) s += hist[base + i];
    seg[t] = s; }
  __syncthreads();
  if (t == 0) {
    int cb = INT_MAX, R = 0;
    if (target > 0) {
      int cum = 0, si = -1;
      for (int i = 255; i >= 0; i--) { if (cum + seg[i] >= target) { si = i; break; } cum += seg[i]; }
      for (int j = si * 32 + 31; j >= si * 32; j--) {
        if (cum + hist[j] >= target) { cb = j; R = target - cum; break; }
        cum += hist[j];
      }
    }
    cbR[row * 2 + 0] = cb;
    cbR[row * 2 + 1] = R;
    targets[row] = target;
  }
}

// K5: gather cutoff-bucket candidates (distributed append; order-independent
// downstream since rank is computed from (v,index), not list position).
__global__ __launch_bounds__(256) void cand_k(const int* __restrict__ labels,
                                              const uint32_t* __restrict__ vpos,
                                              const uint32_t* __restrict__ vneg,
                                              const int* __restrict__ cbR,
                                              int* __restrict__ ccnt,
                                              uint32_t* __restrict__ cvv,
                                              int* __restrict__ cii) {
  const int b = blockIdx.y;
  const int a = blockIdx.x * 256 + threadIdx.x;
  size_t idx = (size_t)b * A_ + a;
  int lb = labels[idx];
  if (lb < 0) return;
  int c = (lb == 1) ? 0 : 1;
  int row = b * 2 + c;
  uint32_t v = (c == 0 ? vpos : vneg)[idx];
  if ((int)(v >> 10) == cbR[row * 2]) {
    int p = atomicAdd(&ccnt[row], 1);
    if (p < CAP) { cvv[row * CAP + p] = v; cii[row * CAP + p] = a; }
  }
}

// K6: one distributed pass over all anchors; per-image bce + smoothL1 sums.
// Cutoff-bucket anchors compute their stable rank inline (O(c2)~5).
__global__ __launch_bounds__(256) void loss_k(const float* __restrict__ anchors,
                                              const float* __restrict__ gtb,
                                              const float* __restrict__ cls,
                                              const float* __restrict__ boxp,
                                              const int* __restrict__ labels,
                                              const int* __restrict__ mgt,
                                              const uint32_t* __restrict__ vpos,
                                              const uint32_t* __restrict__ vneg,
                                              const int* __restrict__ cbR,
                                              const int* __restrict__ ccnt,
                                              const uint32_t* __restrict__ cvv,
                                              const int* __restrict__ cii,
                                              float* __restrict__ bsums) {
  const int b = blockIdx.y;
  const int a = blockIdx.x * 256 + threadIdx.x;
  const int t = threadIdx.x;
  __shared__ float redf[256];
  float sb = 0.f, ss = 0.f;
  size_t idx = (size_t)b * A_ + a;
  int lb = labels[idx];
  if (lb >= 0) {
    int c = (lb == 1) ? 0 : 1;
    int row = b * 2 + c;
    uint32_t v = (c == 0 ? vpos : vneg)[idx];
    int bucket = (int)(v >> 10);
    int cb = cbR[row * 2];
    bool kept = bucket > cb;                 // cb==INT_MAX -> never
    if (!kept && bucket == cb) {
      int c2 = ccnt[row]; if (c2 > CAP) c2 = CAP;
      int R = cbR[row * 2 + 1];
      int r = 0;
      for (int j = 0; j < c2; j++) {
        uint32_t vj = cvv[row * CAP + j]; int ij = cii[row * CAP + j];
        if (vj > v || (vj == v && ij < a)) r++;
      }
      kept = (r < R);
    }
    if (kept) {
      int kk = a % K_; int hw = a / K_; int hh = hw / W_; int wx = hw % W_;
      float x  = cls[(((size_t)b * K_ + kk) * H_ + hh) * W_ + wx];
      float sp = fmaxf(x, 0.f) + log1pf(expf(-fabsf(x)));   // logaddexp(x,0)
      sb = (lb == 1) ? (sp - x) : sp;
      if (lb == 1) {
        float4 an = ((const float4*)anchors)[a];
        int    mg = mgt[idx];
        float4 gg = ((const float4*)gtb)[b * G_ + mg];
        float tt[4]; encode4(an, gg, tt);
        for (int cc = 0; cc < 4; cc++) {
          float p = boxp[(((size_t)b * (4 * K_) + (4 * kk + cc)) * H_ + hh) * W_ + wx];
          float d = p - tt[cc];
          float ad = fabsf(d);
          ss += (ad < 1.f) ? (0.5f * d * d) : (ad - 0.5f);
        }
      }
    }
  }
  float sbT = block_reduce_float(sb, redf);
  float ssT = block_reduce_float(ss, redf);
  if (t == 0) {
    if (sbT != 0.f) atomicAdd(&bsums[b * 2 + 0], sbT);
    if (ssT != 0.f) atomicAdd(&bsums[b * 2 + 1], ssT);
  }
}

// K7: combine per-image sums into the 3 outputs.
__global__ void final_k(const float* __restrict__ bsums, const int* __restrict__ targets,
                        float* __restrict__ out) {
  if (threadIdx.x == 0 && blockIdx.x == 0) {
    float cl = 0.f, bl = 0.f;
    for (int b = 0; b < B_; b++) {
      int tp = targets[b * 2 + 0], tn = targets[b * 2 + 1];
      cl += bsums[b * 2 + 0] / fmaxf((float)(tp + tn), 1.f);
      bl += bsums[b * 2 + 1] / fmaxf(4.f * (float)tp, 1.f);
    }
    cl *= 0.125f; bl *= 0.125f;
    out[0] = cl; out[1] = bl; out[2] = cl + bl;
  }
}

static void compute_keys(KeyParams& kp) {
  const uint32_t r0 = 0u, r1 = 42u;        // jax.random.key(42) -> (hi, lo)
#if PARTITIONABLE
  for (int b = 0; b < B_; b++) {
    uint32_t kb0, kb1;
    tf2x32(r0, r1, 0u, (uint32_t)b, kb0, kb1);        // split(root, 8)[b]
    uint32_t a0, a1, c0, c1;
    tf2x32(kb0, kb1, 0u, 0u, a0, a1);                 // split(key)[0] = k1
    tf2x32(kb0, kb1, 0u, 1u, c0, c1);                 // split(key)[1] = k2
    kp.k[b][0] = a0; kp.k[b][1] = a1; kp.k[b][2] = c0; kp.k[b][3] = c1;
  }
#else
  uint32_t o0[8], o1[8], flat[16];
  for (int i = 0; i < 8; i++) tf2x32(r0, r1, (uint32_t)i, (uint32_t)(8 + i), o0[i], o1[i]);
  for (int i = 0; i < 8; i++) { flat[i] = o0[i]; flat[8 + i] = o1[i]; }
  for (int b = 0; b < B_; b++) {
    uint32_t kb0 = flat[2 * b], kb1 = flat[2 * b + 1];
    uint32_t a0, b0, a1, b1;
    tf2x32(kb0, kb1, 0u, 2u, a0, b0);
    tf2x32(kb0, kb1, 1u, 3u, a1, b1);
    kp.k[b][0] = a0; kp.k[b][1] = a1; kp.k[b][2] = b0; kp.k[b][3] = b1;
  }
#endif
}

extern "C" void kernel_launch(void* const* d_in, const int* in_sizes, int n_in,
                              void* d_out, int out_size, void* d_ws, size_t ws_size,
                              hipStream_t stream) {
  const float* cls     = (const float*)d_in[0];   // [B,K,H,W]
  const float* boxp    = (const float*)d_in[1];   // [B,4K,H,W]
  const float* anchors = (const float*)d_in[2];   // [A,4]
  const float* gtb     = (const float*)d_in[3];   // [B,G,4]
  float* out = (float*)d_out;

  uint8_t* w = (uint8_t*)d_ws;
  // zeroed region [0, 532672): gmax + ghist + counts + ccnt + bsums
  unsigned long long* gmax = (unsigned long long*)w;    // B*G u64 (8 KB)
  int*      ghist   = (int*)(w + 8192);                 // 16*NBUCK ints (512 KB)
  int*      counts  = (int*)(w + 532480);               // 16
  int*      ccnt    = counts + 16;                      // 16
  float*    bsums   = (float*)(ccnt + 16);              // 16
  // non-zeroed region
  int*      labels  = (int*)(w + 532672);               // B*A
  int*      mgt     = labels + (size_t)B_ * A_;         // B*A
  uint32_t* vpos    = (uint32_t*)(mgt + (size_t)B_ * A_);  // B*A
  uint32_t* vneg    = vpos + (size_t)B_ * A_;           // B*A
  int*      cbR     = (int*)(vneg + (size_t)B_ * A_);   // 32
  int*      targets = cbR + 32;                         // 16
  uint32_t* cvv     = (uint32_t*)(targets + 16);        // 16*CAP
  int*      cii     = (int*)(cvv + 16 * CAP);           // 16*CAP

  KeyParams kp;
  compute_keys(kp);

  (void)hipMemsetAsync(w, 0, 532672, stream);
  best_anchor_k<<<dim3(B_ * G_, 4), 256, 0, stream>>>(anchors, gtb, gmax);
  label_k<<<dim3(A_ / 64, B_), 64, 0, stream>>>(anchors, gtb, labels, mgt,
                                                vpos, vneg, ghist, counts, kp);
  force_k<<<(B_ * G_) / 256, 256, 0, stream>>>(gmax, labels, vpos, vneg, ghist, counts);
  cutoff_k<<<16, 256, 0, stream>>>(ghist, counts, cbR, targets);
  cand_k<<<dim3(A_ / 256, B_), 256, 0, stream>>>(labels, vpos, vneg, cbR, ccnt, cvv, cii);
  loss_k<<<dim3(A_ / 256, B_), 256, 0, stream>>>(anchors, gtb, cls, boxp, labels, mgt,
                                                 vpos, vneg, cbR, ccnt, cvv, cii, bsums);
  final_k<<<1, 64, 0, stream>>>(bsums, targets, out);
}

// Round 8
// 174.824 us; speedup vs baseline: 1.5252x; 1.5252x over previous
//
#include <hip/hip_runtime.h>
#include <stdint.h>
#include <limits.h>

// ---------------------------------------------------------------------------
// RPN loss, bit-exact replication of the JAX reference (incl. threefry PRNG).
// Round 8: revert r7's block=64 label_k (120us, staging x4 + unhidden LDS
// latency) back to r5's proven block=256 loop (48.6us), with only the free
// area_a register hoist. NEW: best_anchor_k and label_k fused into ONE
// launch (1D grid: 4096 best-blocks + 1152 label-blocks, branch on bid) --
// removes a ~10us dispatch boundary and fills 256 CUs with 5248 blocks.
// Rule from r3/r4 stands: no cross-thread communication inside the g-loop.
// pack = iou_bits<<32 | ~a : max == (higher iou, then smaller anchor index).
// ---------------------------------------------------------------------------
#define PARTITIONABLE 1

#define B_ 8
#define K_ 9
#define H_ 64
#define W_ 64
#define G_ 128
#define A_ 36864            // K*H*W
#define HALF_A 18432
#define QUART_A 9216
#define NBUCK 8192          // buckets over 23-bit v (v>>10)
#define CAP 1024            // cutoff-bucket candidate capacity (expected ~5)
#define NBEST 4096          // best-anchor blocks in fused grid (1024 bg x 4)
#define NLAB  1152          // label blocks in fused grid (144 x 8)

struct KeyParams { uint32_t k[B_][4]; };   // per image: k1.(0,1), k2.(0,1)

__host__ __device__ static inline uint32_t rotl32(uint32_t x, int r) {
  return (x << r) | (x >> (32 - r));
}

// JAX threefry2x32: 20 rounds, key injections every 4 rounds.
__host__ __device__ static inline void tf2x32(uint32_t k0, uint32_t k1,
                                              uint32_t x0, uint32_t x1,
                                              uint32_t& o0, uint32_t& o1) {
  uint32_t ks2 = k0 ^ k1 ^ 0x1BD11BDAu;
  x0 += k0; x1 += k1;
#define TF_R(r) { x0 += x1; x1 = rotl32(x1, r); x1 ^= x0; }
  TF_R(13) TF_R(15) TF_R(26) TF_R(6)
  x0 += k1;  x1 += ks2 + 1u;
  TF_R(17) TF_R(29) TF_R(16) TF_R(24)
  x0 += ks2; x1 += k0 + 2u;
  TF_R(13) TF_R(15) TF_R(26) TF_R(6)
  x0 += k0;  x1 += k1 + 3u;
  TF_R(17) TF_R(29) TF_R(16) TF_R(24)
  x0 += k1;  x1 += ks2 + 4u;
  TF_R(13) TF_R(15) TF_R(26) TF_R(6)
  x0 += ks2; x1 += k0 + 5u;
#undef TF_R
  o0 = x0; o1 = x1;
}

// 23-bit sort key of jax.random.uniform(key,(A,))[a]; score monotone in v,
// score ties <=> equal v (stable argsort -> smaller index ranks first).
__device__ static inline uint32_t anchor_vbits(uint32_t k0, uint32_t k1, int a) {
  uint32_t o0, o1;
#if PARTITIONABLE
  tf2x32(k0, k1, 0u, (uint32_t)a, o0, o1);
  return (o0 ^ o1) >> 9;
#else
  if (a < HALF_A) { tf2x32(k0, k1, (uint32_t)a, (uint32_t)(a + HALF_A), o0, o1); return o0 >> 9; }
  else            { tf2x32(k0, k1, (uint32_t)(a - HALF_A), (uint32_t)a, o0, o1); return o1 >> 9; }
#endif
}

// Box area, contraction off (bit-identical to XLA's plain fp32 ops).
__device__ static inline float area_of(float x0, float y0, float x1, float y1) {
#pragma clang fp contract(off)
  return (x1 - x0) * (y1 - y0);
}

// IoU, contraction off to match XLA-CPU plain IEEE fp32 op-by-op.
__device__ static inline float iou_fn(float a0, float a1, float a2, float a3,
                                      float g0, float g1, float g2, float g3) {
#pragma clang fp contract(off)
  float ltx = fmaxf(a0, g0), lty = fmaxf(a1, g1);
  float rbx = fminf(a2, g2), rby = fminf(a3, g3);
  float w = rbx - ltx; w = (w < 0.f) ? 0.f : w;
  float h = rby - lty; h = (h < 0.f) ? 0.f : h;
  float inter  = w * h;
  float area_a = (a2 - a0) * (a3 - a1);
  float area_g = (g2 - g0) * (g3 - g1);
  return inter / (area_a + area_g - inter + 1e-6f);
}

// Variant with anchor area hoisted (bit-identical product, XLA order).
__device__ static inline float iou_pre_a(float a0, float a1, float a2, float a3,
                                         float area_a,
                                         float g0, float g1, float g2, float g3) {
#pragma clang fp contract(off)
  float ltx = fmaxf(a0, g0), lty = fmaxf(a1, g1);
  float rbx = fminf(a2, g2), rby = fminf(a3, g3);
  float w = rbx - ltx; w = (w < 0.f) ? 0.f : w;
  float h = rby - lty; h = (h < 0.f) ? 0.f : h;
  float inter  = w * h;
  float area_g = (g2 - g0) * (g3 - g1);
  return inter / (area_a + area_g - inter + 1e-6f);
}

__device__ static inline void encode4(float4 an, float4 gg, float* tt) {
#pragma clang fp contract(off)
  float aw  = an.z - an.x,            ah  = an.w - an.y;
  float acx = (an.x + an.z) * 0.5f,   acy = (an.y + an.w) * 0.5f;
  float gw  = gg.z - gg.x,            gh  = gg.w - gg.y;
  float gcx = (gg.x + gg.z) * 0.5f,   gcy = (gg.y + gg.w) * 0.5f;
  tt[0] = (gcx - acx) / aw;
  tt[1] = (gcy - acy) / ah;
  tt[2] = logf(gw / aw);
  tt[3] = logf(gh / ah);
}

__device__ static inline int block_reduce_int(int v, int* sh) {
  int t = threadIdx.x;
  sh[t] = v; __syncthreads();
  for (int s = 128; s > 0; s >>= 1) { if (t < s) sh[t] += sh[t + s]; __syncthreads(); }
  int r = sh[0]; __syncthreads();
  return r;
}
__device__ static inline float block_reduce_float(float v, float* sh) {
  int t = threadIdx.x;
  sh[t] = v; __syncthreads();
  for (int s = 128; s > 0; s >>= 1) { if (t < s) sh[t] += sh[t + s]; __syncthreads(); }
  float r = sh[0]; __syncthreads();
  return r;
}

__device__ static inline unsigned long long pack_vi(float v, int a) {
  return ((unsigned long long)__float_as_uint(v) << 32) | (uint32_t)(~(uint32_t)a);
}

// K1 (fused): bid < NBEST  -> per-(b,g) x anchor-quarter best-anchor argmax
//             bid >= NBEST -> per-(b,a) label/mgt/PRNG/hist/counts (r5 body)
__global__ __launch_bounds__(256) void fused_iou_k(const float* __restrict__ anchors,
                                                   const float* __restrict__ gtb,
                                                   int* __restrict__ labels,
                                                   int* __restrict__ mgt,
                                                   uint32_t* __restrict__ vpos,
                                                   uint32_t* __restrict__ vneg,
                                                   int* __restrict__ ghist,
                                                   int* __restrict__ counts,
                                                   unsigned long long* __restrict__ gmax,
                                                   KeyParams kp) {
  __shared__ unsigned long long sp[256];   // best path
  __shared__ float4 gts[G_];               // label path
  __shared__ int red[256];                 // label path
  const int bid = blockIdx.x;
  const int t = threadIdx.x;

  if (bid < NBEST) {
    // ---------------- best-anchor path (r6b body, verified) ----------------
    const int bg = bid & 1023;              // b*G + g
    const int base = (bid >> 10) * QUART_A; // anchor quarter
    float4 gg = ((const float4*)gtb)[bg];
    float v0 = -1.f, v1 = -1.f, v2 = -1.f, v3 = -1.f;
    int   i0 = 0,    i1 = 0,    i2 = 0,    i3 = 0;
    // QUART_A/1024 = 9 full iterations; each stream is increasing-a, so
    // strict > keeps the first (smallest) index within the stream.
    for (int a = base + t; a < base + QUART_A; a += 1024) {
      float4 an0 = ((const float4*)anchors)[a];
      float4 an1 = ((const float4*)anchors)[a + 256];
      float4 an2 = ((const float4*)anchors)[a + 512];
      float4 an3 = ((const float4*)anchors)[a + 768];
      float w0 = iou_fn(an0.x, an0.y, an0.z, an0.w, gg.x, gg.y, gg.z, gg.w);
      float w1 = iou_fn(an1.x, an1.y, an1.z, an1.w, gg.x, gg.y, gg.z, gg.w);
      float w2 = iou_fn(an2.x, an2.y, an2.z, an2.w, gg.x, gg.y, gg.z, gg.w);
      float w3 = iou_fn(an3.x, an3.y, an3.z, an3.w, gg.x, gg.y, gg.z, gg.w);
      if (w0 > v0) { v0 = w0; i0 = a; }
      if (w1 > v1) { v1 = w1; i1 = a + 256; }
      if (w2 > v2) { v2 = w2; i2 = a + 512; }
      if (w3 > v3) { v3 = w3; i3 = a + 768; }
    }
    // combine: packed max == (higher iou, then smaller anchor index)
    unsigned long long p = pack_vi(v0, i0);
    unsigned long long q = pack_vi(v1, i1); if (q > p) p = q;
    q = pack_vi(v2, i2); if (q > p) p = q;
    q = pack_vi(v3, i3); if (q > p) p = q;
    sp[t] = p; __syncthreads();
    for (int s = 128; s > 0; s >>= 1) {
      if (t < s) { if (sp[t + s] > sp[t]) sp[t] = sp[t + s]; }
      __syncthreads();
    }
    if (t == 0) atomicMax(&gmax[bg], sp[0]);   // no-return, once/block
    return;
  }

  // ------------------- label path (r5 body + area_a hoist) -----------------
  const int r = bid - NBEST;
  const int b = r / (A_ / 256);
  const int xb = r % (A_ / 256);
  for (int i = t; i < G_; i += 256) gts[i] = ((const float4*)gtb)[b * G_ + i];
  __syncthreads();
  const int a = xb * 256 + t;             // < A_ exactly
  float4 an = ((const float4*)anchors)[a];
  float area_a = area_of(an.x, an.y, an.z, an.w);
  float bv = -1.f; int bi = 0;
#pragma unroll 4
  for (int g = 0; g < G_; g++) {
    float4 gg = gts[g];
    float v = iou_pre_a(an.x, an.y, an.z, an.w, area_a,
                        gg.x, gg.y, gg.z, gg.w);
    if (v > bv) { bv = v; bi = g; }       // first-occurrence argmax over g
  }
  int lb = (bv < 0.3f) ? 0 : ((bv >= 0.7f) ? 1 : -1);
  size_t idx = (size_t)b * A_ + a;
  uint32_t vp = anchor_vbits(kp.k[b][0], kp.k[b][1], a);
  uint32_t vn = anchor_vbits(kp.k[b][2], kp.k[b][3], a);
  labels[idx] = lb;
  mgt[idx]    = bi;
  vpos[idx]   = vp;
  vneg[idx]   = vn;
  if (lb == 1)      atomicAdd(&ghist[(b * 2 + 0) * NBUCK + (vp >> 10)], 1);
  else if (lb == 0) atomicAdd(&ghist[(b * 2 + 1) * NBUCK + (vn >> 10)], 1);
  // packed counts: pos | neg<<16 (block sums <= 256, safe)
  int packed = (lb == 1 ? 1 : 0) | ((lb == 0 ? 1 : 0) << 16);
  int rr = block_reduce_int(packed, red);
  if (t == 0) {
    atomicAdd(&counts[b * 2 + 0], rr & 0xFFFF);
    atomicAdd(&counts[b * 2 + 1], rr >> 16);
  }
}

// K2: force best anchor per gt to 1; patch counts + histograms incrementally.
// atomicExch detects the first forcing of a shared anchor.
__global__ void force_k(const unsigned long long* __restrict__ gmax,
                        int* __restrict__ labels,
                        const uint32_t* __restrict__ vpos,
                        const uint32_t* __restrict__ vneg,
                        int* __restrict__ ghist,
                        int* __restrict__ counts) {
  int tg = blockIdx.x * 256 + threadIdx.x;   // < B_*G_ exactly (4 blocks)
  int b = tg / G_;
  int a = (int)(~(uint32_t)(gmax[tg] & 0xFFFFFFFFull));
  size_t idx = (size_t)b * A_ + a;
  int old = atomicExch(&labels[idx], 1);
  if (old != 1) {
    atomicAdd(&counts[b * 2 + 0], 1);
    atomicAdd(&ghist[(b * 2 + 0) * NBUCK + (vpos[idx] >> 10)], 1);
    if (old == 0) {
      atomicSub(&counts[b * 2 + 1], 1);
      atomicSub(&ghist[(b * 2 + 1) * NBUCK + (vneg[idx] >> 10)], 1);
    }
  }
}

// K3: per (b,c): target + exact cutoff bucket cb and in-bucket remainder R.
__global__ __launch_bounds__(256) void cutoff_k(const int* __restrict__ ghist,
                                                const int* __restrict__ counts,
                                                int* __restrict__ cbR,
                                                int* __restrict__ targets) {
  const int row = blockIdx.x;               // b*2 + c
  const int b = row >> 1, c = row & 1;
  const int t = threadIdx.x;
  __shared__ int seg[256];
  int npos = counts[b * 2 + 0], nneg = counts[b * 2 + 1];
  int tp = npos < 128 ? npos : 128;
  int tn = 256 - tp; if (nneg < tn) tn = nneg;
  const int target = (c == 0) ? tp : tn;
  const int* hist = ghist + (size_t)row * NBUCK;
  { int s = 0; const int base = t * 32;
    for (int i = 0; i < 32; i++) s += hist[base + i];
    seg[t] = s; }
  __syncthreads();
  if (t == 0) {
    int cb = INT_MAX, R = 0;
    if (target > 0) {
      int cum = 0, si = -1;
      for (int i = 255; i >= 0; i--) { if (cum + seg[i] >= target) { si = i; break; } cum += seg[i]; }
      for (int j = si * 32 + 31; j >= si * 32; j--) {
        if (cum + hist[j] >= target) { cb = j; R = target - cum; break; }
        cum += hist[j];
      }
    }
    cbR[row * 2 + 0] = cb;
    cbR[row * 2 + 1] = R;
    targets[row] = target;
  }
}

// K4: gather cutoff-bucket candidates (distributed append; order-independent
// downstream since rank is computed from (v,index), not list position).
__global__ __launch_bounds__(256) void cand_k(const int* __restrict__ labels,
                                              const uint32_t* __restrict__ vpos,
                                              const uint32_t* __restrict__ vneg,
                                              const int* __restrict__ cbR,
                                              int* __restrict__ ccnt,
                                              uint32_t* __restrict__ cvv,
                                              int* __restrict__ cii) {
  const int b = blockIdx.y;
  const int a = blockIdx.x * 256 + threadIdx.x;
  size_t idx = (size_t)b * A_ + a;
  int lb = labels[idx];
  if (lb < 0) return;
  int c = (lb == 1) ? 0 : 1;
  int row = b * 2 + c;
  uint32_t v = (c == 0 ? vpos : vneg)[idx];
  if ((int)(v >> 10) == cbR[row * 2]) {
    int p = atomicAdd(&ccnt[row], 1);
    if (p < CAP) { cvv[row * CAP + p] = v; cii[row * CAP + p] = a; }
  }
}

// K5: one distributed pass over all anchors; per-image bce + smoothL1 sums.
// Cutoff-bucket anchors compute their stable rank inline (O(c2)~5).
__global__ __launch_bounds__(256) void loss_k(const float* __restrict__ anchors,
                                              const float* __restrict__ gtb,
                                              const float* __restrict__ cls,
                                              const float* __restrict__ boxp,
                                              const int* __restrict__ labels,
                                              const int* __restrict__ mgt,
                                              const uint32_t* __restrict__ vpos,
                                              const uint32_t* __restrict__ vneg,
                                              const int* __restrict__ cbR,
                                              const int* __restrict__ ccnt,
                                              const uint32_t* __restrict__ cvv,
                                              const int* __restrict__ cii,
                                              float* __restrict__ bsums) {
  const int b = blockIdx.y;
  const int a = blockIdx.x * 256 + threadIdx.x;
  const int t = threadIdx.x;
  __shared__ float redf[256];
  float sb = 0.f, ss = 0.f;
  size_t idx = (size_t)b * A_ + a;
  int lb = labels[idx];
  if (lb >= 0) {
    int c = (lb == 1) ? 0 : 1;
    int row = b * 2 + c;
    uint32_t v = (c == 0 ? vpos : vneg)[idx];
    int bucket = (int)(v >> 10);
    int cb = cbR[row * 2];
    bool kept = bucket > cb;                 // cb==INT_MAX -> never
    if (!kept && bucket == cb) {
      int c2 = ccnt[row]; if (c2 > CAP) c2 = CAP;
      int R = cbR[row * 2 + 1];
      int r = 0;
      for (int j = 0; j < c2; j++) {
        uint32_t vj = cvv[row * CAP + j]; int ij = cii[row * CAP + j];
        if (vj > v || (vj == v && ij < a)) r++;
      }
      kept = (r < R);
    }
    if (kept) {
      int kk = a % K_; int hw = a / K_; int hh = hw / W_; int wx = hw % W_;
      float x  = cls[(((size_t)b * K_ + kk) * H_ + hh) * W_ + wx];
      float sp = fmaxf(x, 0.f) + log1pf(expf(-fabsf(x)));   // logaddexp(x,0)
      sb = (lb == 1) ? (sp - x) : sp;
      if (lb == 1) {
        float4 an = ((const float4*)anchors)[a];
        int    mg = mgt[idx];
        float4 gg = ((const float4*)gtb)[b * G_ + mg];
        float tt[4]; encode4(an, gg, tt);
        for (int cc = 0; cc < 4; cc++) {
          float p = boxp[(((size_t)b * (4 * K_) + (4 * kk + cc)) * H_ + hh) * W_ + wx];
          float d = p - tt[cc];
          float ad = fabsf(d);
          ss += (ad < 1.f) ? (0.5f * d * d) : (ad - 0.5f);
        }
      }
    }
  }
  float sbT = block_reduce_float(sb, redf);
  float ssT = block_reduce_float(ss, redf);
  if (t == 0) {
    if (sbT != 0.f) atomicAdd(&bsums[b * 2 + 0], sbT);
    if (ssT != 0.f) atomicAdd(&bsums[b * 2 + 1], ssT);
  }
}

// K6: combine per-image sums into the 3 outputs.
__global__ void final_k(const float* __restrict__ bsums, const int* __restrict__ targets,
                        float* __restrict__ out) {
  if (threadIdx.x == 0 && blockIdx.x == 0) {
    float cl = 0.f, bl = 0.f;
    for (int b = 0; b < B_; b++) {
      int tp = targets[b * 2 + 0], tn = targets[b * 2 + 1];
      cl += bsums[b * 2 + 0] / fmaxf((float)(tp + tn), 1.f);
      bl += bsums[b * 2 + 1] / fmaxf(4.f * (float)tp, 1.f);
    }
    cl *= 0.125f; bl *= 0.125f;
    out[0] = cl; out[1] = bl; out[2] = cl + bl;
  }
}

static void compute_keys(KeyParams& kp) {
  const uint32_t r0 = 0u, r1 = 42u;        // jax.random.key(42) -> (hi, lo)
#if PARTITIONABLE
  for (int b = 0; b < B_; b++) {
    uint32_t kb0, kb1;
    tf2x32(r0, r1, 0u, (uint32_t)b, kb0, kb1);        // split(root, 8)[b]
    uint32_t a0, a1, c0, c1;
    tf2x32(kb0, kb1, 0u, 0u, a0, a1);                 // split(key)[0] = k1
    tf2x32(kb0, kb1, 0u, 1u, c0, c1);                 // split(key)[1] = k2
    kp.k[b][0] = a0; kp.k[b][1] = a1; kp.k[b][2] = c0; kp.k[b][3] = c1;
  }
#else
  uint32_t o0[8], o1[8], flat[16];
  for (int i = 0; i < 8; i++) tf2x32(r0, r1, (uint32_t)i, (uint32_t)(8 + i), o0[i], o1[i]);
  for (int i = 0; i < 8; i++) { flat[i] = o0[i]; flat[8 + i] = o1[i]; }
  for (int b = 0; b < B_; b++) {
    uint32_t kb0 = flat[2 * b], kb1 = flat[2 * b + 1];
    uint32_t a0, b0, a1, b1;
    tf2x32(kb0, kb1, 0u, 2u, a0, b0);
    tf2x32(kb0, kb1, 1u, 3u, a1, b1);
    kp.k[b][0] = a0; kp.k[b][1] = a1; kp.k[b][2] = b0; kp.k[b][3] = b1;
  }
#endif
}

extern "C" void kernel_launch(void* const* d_in, const int* in_sizes, int n_in,
                              void* d_out, int out_size, void* d_ws, size_t ws_size,
                              hipStream_t stream) {
  const float* cls     = (const float*)d_in[0];   // [B,K,H,W]
  const float* boxp    = (const float*)d_in[1];   // [B,4K,H,W]
  const float* anchors = (const float*)d_in[2];   // [A,4]
  const float* gtb     = (const float*)d_in[3];   // [B,G,4]
  float* out = (float*)d_out;

  uint8_t* w = (uint8_t*)d_ws;
  // zeroed region [0, 532672): gmax + ghist + counts + ccnt + bsums
  unsigned long long* gmax = (unsigned long long*)w;    // B*G u64 (8 KB)
  int*      ghist   = (int*)(w + 8192);                 // 16*NBUCK ints (512 KB)
  int*      counts  = (int*)(w + 532480);               // 16
  int*      ccnt    = counts + 16;                      // 16
  float*    bsums   = (float*)(ccnt + 16);              // 16
  // non-zeroed region
  int*      labels  = (int*)(w + 532672);               // B*A
  int*      mgt     = labels + (size_t)B_ * A_;         // B*A
  uint32_t* vpos    = (uint32_t*)(mgt + (size_t)B_ * A_);  // B*A
  uint32_t* vneg    = vpos + (size_t)B_ * A_;           // B*A
  int*      cbR     = (int*)(vneg + (size_t)B_ * A_);   // 32
  int*      targets = cbR + 32;                         // 16
  uint32_t* cvv     = (uint32_t*)(targets + 16);        // 16*CAP
  int*      cii     = (int*)(cvv + 16 * CAP);           // 16*CAP

  KeyParams kp;
  compute_keys(kp);

  (void)hipMemsetAsync(w, 0, 532672, stream);
  fused_iou_k<<<NBEST + NLAB, 256, 0, stream>>>(anchors, gtb, labels, mgt,
                                                vpos, vneg, ghist, counts, gmax, kp);
  force_k<<<(B_ * G_) / 256, 256, 0, stream>>>(gmax, labels, vpos, vneg, ghist, counts);
  cutoff_k<<<16, 256, 0, stream>>>(ghist, counts, cbR, targets);
  cand_k<<<dim3(A_ / 256, B_), 256, 0, stream>>>(labels, vpos, vneg, cbR, ccnt, cvv, cii);
  loss_k<<<dim3(A_ / 256, B_), 256, 0, stream>>>(anchors, gtb, cls, boxp, labels, mgt,
                                                 vpos, vneg, cbR, ccnt, cvv, cii, bsums);
  final_k<<<1, 64, 0, stream>>>(bsums, targets, out);
}